// Round 1
// baseline (797.143 us; speedup 1.0000x reference)
//
#include <hip/hip_runtime.h>

// Problem constants (fixed by reference)
#define BB 256      // batch
#define TT 1024     // time steps
#define HH 32       // hidden
#define LL 3        // GRU layers
#define GG 96       // 3*H gate rows
#define NT 448      // threads per block (7 waves)

// Pipeline stages at tick tau:
//   E  : prefetch emb row for t=tau+1 (written to ebuf in phase B)
//   M1 : y1(t=tau)   = relu(W1 @ e(t)   + b1)
//   M2 : y2(t=tau-1) = relu(W2 @ y1(t)  + b2)
//   M3 : y3(t=tau-2) = relu(W3 @ y2(t)  + b3)
//   L0 : GRU layer 0 at t=tau-3  (input y3)
//   L1 : GRU layer 1 at t=tau-4  (input h0 stream)
//   L2 : GRU layer 2 at t=tau-5  (input h1 stream) -> global out
// Total ticks = TT + 5.

__device__ __forceinline__ float fast_rcp(float x) { return __builtin_amdgcn_rcpf(x); }
__device__ __forceinline__ float sigm(float x)     { return fast_rcp(1.f + __expf(-x)); }
__device__ __forceinline__ float tanh_fast(float x){ float e = __expf(2.f * x); return 1.f - 2.f * fast_rcp(e + 1.f); }

__global__ __launch_bounds__(NT, 1) void rnn_fused(
    const int*   __restrict__ xidx,   // [B,T]
    const float* __restrict__ hid,    // [L,B,H]
    const float* __restrict__ emb,    // [38000,H]
    const float* __restrict__ W1, const float* __restrict__ b1,
    const float* __restrict__ W2, const float* __restrict__ b2,
    const float* __restrict__ W3, const float* __restrict__ b3,
    const float* __restrict__ Wih,    // [L,3H,H]
    const float* __restrict__ Whh,    // [L,3H,H]
    const float* __restrict__ bih,    // [L,3H]
    const float* __restrict__ bhh,    // [L,3H]
    float*       __restrict__ out)    // [B*T*H] ++ [L*B*H]
{
    const int b   = blockIdx.x;
    const int tid = threadIdx.x;

    __shared__ int idxbuf[TT];                      // token ids for this batch row
    __shared__ alignas(16) float ebuf[HH];          // emb row e(tau) at tick start
    __shared__ alignas(16) float ybuf[3][HH];       // y1,y2,y3 (MLP stage outputs)
    __shared__ alignas(16) float xbuf[2][HH];       // layer0->1, layer1->2 streams
    __shared__ alignas(16) float hbuf[LL][HH];      // GRU hidden states
    __shared__ alignas(16) float gibuf[LL][GG];     // input-side gate dots
    __shared__ alignas(16) float ghbuf[LL][GG];     // hidden-side gate dots

    // ---- thread roles (wave-aligned groups) ----
    // tid   0..287 : L-dots (layer l = tid/96, gate row g = tid%96)  [waves 0-4 low]
    // tid 288..319 : idle                                            [wave 4 high]
    // tid 320..415 : M-dots + gate combine (stage ms, unit mo)       [wave 5, wave 6 low]
    // tid 416..447 : E emb prefetch                                  [wave 6 high]
    const bool isL = (tid < 288);
    const int  l   = tid / 96;
    const int  g   = tid % 96;
    const bool isM = (tid >= 320) && (tid < 416);
    const int  ms  = (tid - 320) >> 5;
    const int  mo  = (tid - 320) & 31;
    const bool isE = (tid >= 416);
    const int  el  = tid - 416;

    // ---- weights into registers ----
    float4 wA[8], wB[8]; float biA = 0.f, biB = 0.f;   // L: W_ih row / W_hh row
    float4 wM[8];        float bM  = 0.f;              // M: W{1,2,3} row
    if (isL) {
        const float4* pA = reinterpret_cast<const float4*>(Wih + (size_t)(l * GG + g) * HH);
        const float4* pB = reinterpret_cast<const float4*>(Whh + (size_t)(l * GG + g) * HH);
        #pragma unroll
        for (int i = 0; i < 8; ++i) { wA[i] = pA[i]; wB[i] = pB[i]; }
        biA = bih[l * GG + g];
        biB = bhh[l * GG + g];
    } else if (isM) {
        const float* Ws = (ms == 0) ? W1 : (ms == 1) ? W2 : W3;
        const float* bs = (ms == 0) ? b1 : (ms == 1) ? b2 : b3;
        const float4* pW = reinterpret_cast<const float4*>(Ws + mo * HH);
        #pragma unroll
        for (int i = 0; i < 8; ++i) wM[i] = pW[i];
        bM = bs[mo];
    }

    // loop-invariant LDS source pointers
    const float4* xpL = nullptr;  // L-dot x source
    const float4* hpL = reinterpret_cast<const float4*>(hbuf[isL ? l : 0]);
    if (isL) xpL = reinterpret_cast<const float4*>((l == 0) ? ybuf[2] : xbuf[l - 1]);
    const float4* ipM = nullptr;  // M-dot input source
    if (isM) ipM = reinterpret_cast<const float4*>((ms == 0) ? ebuf : ybuf[ms - 1]);

    // ---- preload indices + initial hidden ----
    for (int t = tid; t < TT; t += NT) idxbuf[t] = xidx[b * TT + t];
    if (tid < LL * HH) {
        const int ll = tid / HH, oo = tid % HH;
        hbuf[ll][oo] = hid[(size_t)(ll * BB + b) * HH + oo];
    }
    __syncthreads();

    // ---- prime the embedding pipeline: ebuf = e(0), pend = e(1) ----
    float pend = 0.f;
    if (isE) {
        ebuf[el] = emb[(size_t)idxbuf[0] * HH + el];
        pend     = emb[(size_t)idxbuf[1] * HH + el];
    }
    __syncthreads();

    float* const out_seq = out + (size_t)b * TT * HH;          // [T,H] slab for this b
    float* const out_hf  = out + (size_t)BB * TT * HH;         // h_finals base

    for (int tau = 0; tau < TT + 5; ++tau) {
        // ================= phase A : all dot products =================
        float ym = 0.f; bool mAct = false;
        if (isL) {
            const int t = tau - 3 - l;
            if (t >= 0 && t < TT) {
                float gi0 = biA, gi1 = 0.f, gh0 = biB, gh1 = 0.f;
                #pragma unroll
                for (int i = 0; i < 8; i += 2) {
                    const float4 xa = xpL[i], xb = xpL[i + 1];
                    const float4 ha = hpL[i], hb = hpL[i + 1];
                    gi0 = fmaf(wA[i].x,     xa.x, gi0);
                    gi0 = fmaf(wA[i].y,     xa.y, gi0);
                    gi0 = fmaf(wA[i].z,     xa.z, gi0);
                    gi0 = fmaf(wA[i].w,     xa.w, gi0);
                    gi1 = fmaf(wA[i + 1].x, xb.x, gi1);
                    gi1 = fmaf(wA[i + 1].y, xb.y, gi1);
                    gi1 = fmaf(wA[i + 1].z, xb.z, gi1);
                    gi1 = fmaf(wA[i + 1].w, xb.w, gi1);
                    gh0 = fmaf(wB[i].x,     ha.x, gh0);
                    gh0 = fmaf(wB[i].y,     ha.y, gh0);
                    gh0 = fmaf(wB[i].z,     ha.z, gh0);
                    gh0 = fmaf(wB[i].w,     ha.w, gh0);
                    gh1 = fmaf(wB[i + 1].x, hb.x, gh1);
                    gh1 = fmaf(wB[i + 1].y, hb.y, gh1);
                    gh1 = fmaf(wB[i + 1].z, hb.z, gh1);
                    gh1 = fmaf(wB[i + 1].w, hb.w, gh1);
                }
                gibuf[l][g] = gi0 + gi1;
                ghbuf[l][g] = gh0 + gh1;
            }
        } else if (isM) {
            const int t = tau - ms;
            if (t >= 0 && t < TT) {
                mAct = true;
                float a0 = bM, a1 = 0.f;
                #pragma unroll
                for (int i = 0; i < 8; i += 2) {
                    const float4 v0 = ipM[i], v1 = ipM[i + 1];
                    a0 = fmaf(wM[i].x,     v0.x, a0);
                    a0 = fmaf(wM[i].y,     v0.y, a0);
                    a0 = fmaf(wM[i].z,     v0.z, a0);
                    a0 = fmaf(wM[i].w,     v0.w, a0);
                    a1 = fmaf(wM[i + 1].x, v1.x, a1);
                    a1 = fmaf(wM[i + 1].y, v1.y, a1);
                    a1 = fmaf(wM[i + 1].z, v1.z, a1);
                    a1 = fmaf(wM[i + 1].w, v1.w, a1);
                }
                ym = fmaxf(a0 + a1, 0.f);
            }
        }
        __syncthreads();   // dots visible; phase-A reads finished

        // ================= phase B : state update =================
        if (isM) {
            if (mAct) ybuf[ms][mo] = ym;            // MLP stage output
            const int tc = tau - 3 - ms;            // combine for GRU layer ms
            if (tc >= 0 && tc < TT) {
                const float i_r = gibuf[ms][mo];
                const float i_z = gibuf[ms][mo + 32];
                const float i_n = gibuf[ms][mo + 64];
                const float h_r = ghbuf[ms][mo];
                const float h_z = ghbuf[ms][mo + 32];
                const float h_n = ghbuf[ms][mo + 64];
                const float hp  = hbuf[ms][mo];
                const float r = sigm(i_r + h_r);
                const float z = sigm(i_z + h_z);
                const float n = tanh_fast(fmaf(r, h_n, i_n));
                const float hn = fmaf(z, hp - n, n);   // (1-z)*n + z*hp
                hbuf[ms][mo] = hn;
                if (ms < 2) xbuf[ms][mo] = hn;
                else        out_seq[(size_t)tc * HH + mo] = hn;
                if (tc == TT - 1) out_hf[(size_t)(ms * BB + b) * HH + mo] = hn;
            }
        } else if (isE) {
            const int tw = tau + 1;                 // stage e(tau+1) for next tick
            if (tw < TT) ebuf[el] = pend;
            const int tl = tau + 2;                 // prefetch e(tau+2)
            if (tl < TT) pend = emb[(size_t)idxbuf[tl] * HH + el];
        }
        __syncthreads();   // state visible for next tick
    }
}

extern "C" void kernel_launch(void* const* d_in, const int* in_sizes, int n_in,
                              void* d_out, int out_size, void* d_ws, size_t ws_size,
                              hipStream_t stream) {
    const int*   x   = (const int*)  d_in[0];
    const float* hid = (const float*)d_in[1];
    const float* emb = (const float*)d_in[2];
    const float* W1  = (const float*)d_in[3];
    const float* b1  = (const float*)d_in[4];
    const float* W2  = (const float*)d_in[5];
    const float* b2  = (const float*)d_in[6];
    const float* W3  = (const float*)d_in[7];
    const float* b3  = (const float*)d_in[8];
    const float* Wih = (const float*)d_in[9];
    const float* Whh = (const float*)d_in[10];
    const float* bih = (const float*)d_in[11];
    const float* bhh = (const float*)d_in[12];

    rnn_fused<<<dim3(BB), dim3(NT), 0, stream>>>(
        x, hid, emb, W1, b1, W2, b2, W3, b3, Wih, Whh, bih, bhh, (float*)d_out);
}

// Round 4
// 759.911 us; speedup vs baseline: 1.0490x; 1.0490x over previous
//
#include <hip/hip_runtime.h>

// Problem constants (fixed by reference)
#define BB 256      // batch
#define TT 1024     // time steps
#define HH 32       // hidden
#define LL 3        // GRU layers
#define GG 96       // 3*H gate rows
#define NT 448      // threads per block (7 waves)
#define CH 64       // emb prefetch chunk (steps)

// Pipeline stages at tick tau:
//   M1 : y1(t=tau)   = relu(W1 @ e(t)   + b1)     e from double-buffered LDS chunk
//   M2 : y2(t=tau-1) = relu(W2 @ y1(t)  + b2)
//   M3 : y3(t=tau-2) = relu(W3 @ y2(t)  + b3)
//   L0 : GRU layer 0 at t=tau-3  (input y3)
//   L1 : GRU layer 1 at t=tau-4  (input h0 stream)
//   L2 : GRU layer 2 at t=tau-5  (input h1 stream) -> LDS ring, flushed /16
//   F  : (1/64 ticks) prefetch next emb chunk; (1/16 ticks) flush output ring
// Ticks: tau = 0 .. TT+5.

__device__ __forceinline__ float fast_rcp(float x) { return __builtin_amdgcn_rcpf(x); }
__device__ __forceinline__ float sigm(float x)     { return fast_rcp(1.f + __expf(-x)); }
__device__ __forceinline__ float tanh_fast(float x){ float e = __expf(2.f * x); return 1.f - 2.f * fast_rcp(e + 1.f); }

__global__ __launch_bounds__(NT, 1) void rnn_fused(
    const int*   __restrict__ xidx,   // [B,T]
    const float* __restrict__ hid,    // [L,B,H]
    const float* __restrict__ emb,    // [38000,H]
    const float* __restrict__ W1, const float* __restrict__ b1,
    const float* __restrict__ W2, const float* __restrict__ b2,
    const float* __restrict__ W3, const float* __restrict__ b3,
    const float* __restrict__ Wih,    // [L,3H,H]
    const float* __restrict__ Whh,    // [L,3H,H]
    const float* __restrict__ bih,    // [L,3H]
    const float* __restrict__ bhh,    // [L,3H]
    float*       __restrict__ out)    // [B*T*H] ++ [L*B*H]
{
    const int b   = blockIdx.x;
    const int tid = threadIdx.x;

    __shared__ int idxbuf[TT];                        // token ids for this batch row (4 KB)
    __shared__ alignas(16) float ebuf2[2][CH][HH];    // emb chunk double buffer (16 KB)
    __shared__ alignas(16) float ybuf[3][HH];         // y1,y2,y3 (MLP stage outputs)
    __shared__ alignas(16) float xbuf[2][HH];         // layer0->1, layer1->2 streams
    __shared__ alignas(16) float hbuf[LL][HH];        // GRU hidden states
    __shared__ alignas(16) float gibuf[LL][GG];       // input-side gate dots
    __shared__ alignas(16) float ghbuf[LL][GG];       // hidden-side gate dots
    __shared__ alignas(16) float obuf[32][HH];        // layer-2 output ring (4 KB)

    // ---- thread roles (wave-aligned groups) ----
    // tid   0..287 : L-dots (layer l = tid/96, gate row g = tid%96)  [waves 0-4 low]
    // tid 288..319 : idle                                            [wave 4 high]
    // tid 320..415 : M-dots + gate combine (stage ms, unit mo)       [wave 5, wave 6 low]
    // tid 416..447 : F threads: emb chunk prefetch + output flush    [wave 6 high]
    const bool isL = (tid < 288);
    const int  l   = tid / 96;
    const int  g   = tid % 96;
    const bool isM = (tid >= 320) && (tid < 416);
    const int  ms  = (tid - 320) >> 5;
    const int  mo  = (tid - 320) & 31;
    const bool isF = (tid >= 416);
    const int  ff  = tid - 416;

    // ---- weights into registers ----
    float4 wA[8], wB[8]; float biA = 0.f, biB = 0.f;   // L: W_ih row / W_hh row
    float4 wM[8];        float bM  = 0.f;              // M: W{1,2,3} row
    if (isL) {
        const float4* pA = reinterpret_cast<const float4*>(Wih + (size_t)(l * GG + g) * HH);
        const float4* pB = reinterpret_cast<const float4*>(Whh + (size_t)(l * GG + g) * HH);
        #pragma unroll
        for (int i = 0; i < 8; ++i) { wA[i] = pA[i]; wB[i] = pB[i]; }
        biA = bih[l * GG + g];
        biB = bhh[l * GG + g];
    } else if (isM) {
        const float* Ws = (ms == 0) ? W1 : (ms == 1) ? W2 : W3;
        const float* bs = (ms == 0) ? b1 : (ms == 1) ? b2 : b3;
        const float4* pW = reinterpret_cast<const float4*>(Ws + mo * HH);
        #pragma unroll
        for (int i = 0; i < 8; ++i) wM[i] = pW[i];
        bM = bs[mo];
    }

    // loop-invariant LDS source pointers
    const float4* xpL = nullptr;  // L-dot x source
    const float4* hpL = reinterpret_cast<const float4*>(hbuf[isL ? l : 0]);
    if (isL) xpL = reinterpret_cast<const float4*>((l == 0) ? ybuf[2] : xbuf[l - 1]);
    const float4* ipM = nullptr;  // M-dot input source (stages 1,2)
    if (isM && ms > 0) ipM = reinterpret_cast<const float4*>(ybuf[ms - 1]);

    // ---- preload indices + initial hidden ----
    for (int t = tid; t < TT; t += NT) idxbuf[t] = xidx[b * TT + t];
    if (tid < LL * HH) {
        const int ll = tid / HH, oo = tid % HH;
        hbuf[ll][oo] = hid[(size_t)(ll * BB + b) * HH + oo];
    }
    __syncthreads();

    // ---- preload emb chunk 0 (whole block helps) ----
    {
        float4*       dst = reinterpret_cast<float4*>(&ebuf2[0][0][0]);
        const float4* src = reinterpret_cast<const float4*>(emb);
        for (int j = tid; j < CH * 8; j += NT) {
            const int row = j >> 3, q = j & 7;
            dst[row * 8 + q] = src[(size_t)idxbuf[row] * 8 + q];
        }
    }
    __syncthreads();

    float* const out_seq = out + (size_t)b * TT * HH;          // [T,H] slab for this b
    float* const out_hf  = out + (size_t)BB * TT * HH;         // h_finals base

    for (int tau = 0; tau < TT + 6; ++tau) {
        // ================= phase A : dots + (F) prefetch / flush =================
        float ym = 0.f; bool mAct = false;
        if (isL) {
            const int t = tau - 3 - l;
            if (t >= 0 && t < TT) {
                float gi0 = biA, gi1 = 0.f, gh0 = biB, gh1 = 0.f;
                #pragma unroll
                for (int i = 0; i < 8; i += 2) {
                    const float4 xa = xpL[i], xb = xpL[i + 1];
                    const float4 ha = hpL[i], hb = hpL[i + 1];
                    gi0 = fmaf(wA[i].x,     xa.x, gi0);
                    gi0 = fmaf(wA[i].y,     xa.y, gi0);
                    gi0 = fmaf(wA[i].z,     xa.z, gi0);
                    gi0 = fmaf(wA[i].w,     xa.w, gi0);
                    gi1 = fmaf(wA[i + 1].x, xb.x, gi1);
                    gi1 = fmaf(wA[i + 1].y, xb.y, gi1);
                    gi1 = fmaf(wA[i + 1].z, xb.z, gi1);
                    gi1 = fmaf(wA[i + 1].w, xb.w, gi1);
                    gh0 = fmaf(wB[i].x,     ha.x, gh0);
                    gh0 = fmaf(wB[i].y,     ha.y, gh0);
                    gh0 = fmaf(wB[i].z,     ha.z, gh0);
                    gh0 = fmaf(wB[i].w,     ha.w, gh0);
                    gh1 = fmaf(wB[i + 1].x, hb.x, gh1);
                    gh1 = fmaf(wB[i + 1].y, hb.y, gh1);
                    gh1 = fmaf(wB[i + 1].z, hb.z, gh1);
                    gh1 = fmaf(wB[i + 1].w, hb.w, gh1);
                }
                gibuf[l][g] = gi0 + gi1;
                ghbuf[l][g] = gh0 + gh1;
            }
        } else if (isM) {
            const int t = tau - ms;
            if (t >= 0 && t < TT) {
                mAct = true;
                const float4* src = (ms == 0)
                    ? reinterpret_cast<const float4*>(&ebuf2[(t >> 6) & 1][t & (CH - 1)][0])
                    : ipM;
                float a0 = bM, a1 = 0.f;
                #pragma unroll
                for (int i = 0; i < 8; i += 2) {
                    const float4 v0 = src[i], v1 = src[i + 1];
                    a0 = fmaf(wM[i].x,     v0.x, a0);
                    a0 = fmaf(wM[i].y,     v0.y, a0);
                    a0 = fmaf(wM[i].z,     v0.z, a0);
                    a0 = fmaf(wM[i].w,     v0.w, a0);
                    a1 = fmaf(wM[i + 1].x, v1.x, a1);
                    a1 = fmaf(wM[i + 1].y, v1.y, a1);
                    a1 = fmaf(wM[i + 1].z, v1.z, a1);
                    a1 = fmaf(wM[i + 1].w, v1.w, a1);
                }
                ym = fmaxf(a0 + a1, 0.f);
            }
        } else if (isF) {   // <-- guarded: tid 288..319 stay idle (R2/R3 bug was bare else)
            // (a) prefetch next emb chunk at chunk boundaries
            if ((tau & (CH - 1)) == 0) {
                const int cn = (tau >> 6) + 1;        // next chunk
                if (cn < TT / CH) {
                    float4*       dst = reinterpret_cast<float4*>(&ebuf2[cn & 1][0][0]);
                    const float4* src = reinterpret_cast<const float4*>(emb);
                    const int base = cn * CH;
                    #pragma unroll
                    for (int k = 0; k < 16; ++k) {
                        const int j = k * 32 + ff, row = j >> 3, q = j & 7;
                        dst[row * 8 + q] = src[(size_t)idxbuf[base + row] * 8 + q];
                    }
                }
            }
            // (b) flush 16 completed layer-2 outputs every 16 ticks
            const int tcl = tau - 6;                 // last tc whose combine completed
            if (tcl >= 15 && (tcl & 15) == 15) {
                const int half = (tcl & 16) ? 16 : 0; // ring half that is now complete
                const int tc0  = tcl - 15;
                #pragma unroll
                for (int k = 0; k < 4; ++k) {
                    const int j   = k * 32 + ff;      // 128 float4 tasks over 32 lanes
                    const int row = j >> 3, q = j & 7;
                    const float4 v = *reinterpret_cast<const float4*>(&obuf[half + row][q * 4]);
                    *reinterpret_cast<float4*>(&out_seq[(size_t)(tc0 + row) * HH + q * 4]) = v;
                }
            }
        }
        __syncthreads();   // dots visible; phase-A reads finished

        // ================= phase B : state update =================
        if (isM) {
            if (mAct) ybuf[ms][mo] = ym;            // MLP stage output
            const int tc = tau - 3 - ms;            // combine for GRU layer ms
            if (tc >= 0 && tc < TT) {
                const float i_r = gibuf[ms][mo];
                const float i_z = gibuf[ms][mo + 32];
                const float i_n = gibuf[ms][mo + 64];
                const float h_r = ghbuf[ms][mo];
                const float h_z = ghbuf[ms][mo + 32];
                const float h_n = ghbuf[ms][mo + 64];
                const float hp  = hbuf[ms][mo];
                const float r = sigm(i_r + h_r);
                const float z = sigm(i_z + h_z);
                const float n = tanh_fast(fmaf(r, h_n, i_n));
                const float hn = fmaf(z, hp - n, n);   // (1-z)*n + z*hp
                hbuf[ms][mo] = hn;
                if (ms < 2) xbuf[ms][mo] = hn;
                else        obuf[tc & 31][mo] = hn;    // ring; flushed by F threads
                if (tc == TT - 1) out_hf[(size_t)(ms * BB + b) * HH + mo] = hn;
            }
        }
        __syncthreads();   // state visible for next tick
    }
}

extern "C" void kernel_launch(void* const* d_in, const int* in_sizes, int n_in,
                              void* d_out, int out_size, void* d_ws, size_t ws_size,
                              hipStream_t stream) {
    const int*   x   = (const int*)  d_in[0];
    const float* hid = (const float*)d_in[1];
    const float* emb = (const float*)d_in[2];
    const float* W1  = (const float*)d_in[3];
    const float* b1  = (const float*)d_in[4];
    const float* W2  = (const float*)d_in[5];
    const float* b2  = (const float*)d_in[6];
    const float* W3  = (const float*)d_in[7];
    const float* b3  = (const float*)d_in[8];
    const float* Wih = (const float*)d_in[9];
    const float* Whh = (const float*)d_in[10];
    const float* bih = (const float*)d_in[11];
    const float* bhh = (const float*)d_in[12];

    rnn_fused<<<dim3(BB), dim3(NT), 0, stream>>>(
        x, hid, emb, W1, b1, W2, b2, W3, b3, Wih, Whh, bih, bhh, (float*)d_out);
}

// Round 5
// 575.104 us; speedup vs baseline: 1.3861x; 1.3213x over previous
//
#include <hip/hip_runtime.h>

// Problem constants (fixed by reference)
#define BB 256      // batch
#define TT 1024     // time steps
#define HH 32       // hidden
#define LL 3        // GRU layers
#define NT 256      // 4 waves
#define CH 64       // emb chunk length (steps)

// 4 waves, one barrier per tick. Wave roles:
//   wv 0..2 : GRU layer wv, time t = tau-3-wv. h kept in registers (lane j = h[j]).
//             192 dot rows: dotA = rows 0..63 (lane), dotB = rows 64..95 (lane&31).
//   wv 3    : MLP pipeline y1(tau), y2(tau-1), y3(tau-2); y3 -> xstream[0].
//             Also refills emb chunk (1/64 ticks).
//   Layer-2 output -> obuf ring, flushed by wave 2 every 16 ticks.
// Broadcast of x/h vectors via v_readlane -> SGPR (VALU), not LDS reads.

__device__ __forceinline__ float fast_rcp(float x) { return __builtin_amdgcn_rcpf(x); }
__device__ __forceinline__ float sigm(float x)     { return fast_rcp(1.f + __expf(-x)); }
__device__ __forceinline__ float tanh_fast(float x){ float e = __expf(2.f * x); return 1.f - 2.f * fast_rcp(e + 1.f); }
__device__ __forceinline__ float rlane(float v, int k) {
    return __int_as_float(__builtin_amdgcn_readlane(__float_as_int(v), k));
}

__global__ __launch_bounds__(NT, 1) void rnn_fused(
    const int*   __restrict__ xidx,   // [B,T]
    const float* __restrict__ hid,    // [L,B,H]
    const float* __restrict__ emb,    // [38000,H]
    const float* __restrict__ W1, const float* __restrict__ b1,
    const float* __restrict__ W2, const float* __restrict__ b2,
    const float* __restrict__ W3, const float* __restrict__ b3,
    const float* __restrict__ Wih,    // [L,3H,H]
    const float* __restrict__ Whh,    // [L,3H,H]
    const float* __restrict__ bih,    // [L,3H]
    const float* __restrict__ bhh,    // [L,3H]
    float*       __restrict__ out)    // [B*T*H] ++ [L*B*H]
{
    const int b   = blockIdx.x;
    const int tid = threadIdx.x;
    const int wv  = tid >> 6;          // wave id 0..3
    const int ln  = tid & 63;          // lane

    __shared__ int idxbuf[TT];                       // 4 KB
    __shared__ alignas(16) float ebuf[2][CH][HH];    // 16 KB emb chunk dbuf
    __shared__ alignas(16) float xstream[3][2][HH];  // [feed stage][parity][unit]
    __shared__ alignas(16) float obuf[32][HH];       // 4 KB layer-2 ring

    // ---- preload token ids ----
    for (int t = tid; t < TT; t += NT) idxbuf[t] = xidx[b * TT + t];
    __syncthreads();

    // ---- preload emb chunk 0 (512 float4 tasks over 256 threads) ----
    {
        float4*       edst = reinterpret_cast<float4*>(&ebuf[0][0][0]);
        const float4* esrc = reinterpret_cast<const float4*>(emb);
        #pragma unroll
        for (int k = 0; k < 2; ++k) {
            const int task = k * NT + tid, row = task >> 3, q = task & 7;
            edst[row * 8 + q] = esrc[(size_t)idxbuf[row] * 8 + q];
        }
    }

    // ---- per-role registers ----
    float wA[32], wB[32], wC[32], wD[32];
    float bA = 0.f, bB = 0.f, bC = 0.f, bD = 0.f;
    float v_h = 0.f, v_y1p = 0.f, v_y2p = 0.f;

    if (wv < 3) {
        const int rA = ln;               // rows 0..63  (r gates lanes 0-31, z gates lanes 32-63)
        const int rB = 64 + (ln & 31);   // rows 64..95 (n gates; high lanes duplicate)
        const float4* pA = reinterpret_cast<const float4*>(Wih + (size_t)(wv * 96 + rA) * HH);
        const float4* pB = reinterpret_cast<const float4*>(Wih + (size_t)(wv * 96 + rB) * HH);
        const float4* pC = reinterpret_cast<const float4*>(Whh + (size_t)(wv * 96 + rA) * HH);
        const float4* pD = reinterpret_cast<const float4*>(Whh + (size_t)(wv * 96 + rB) * HH);
        #pragma unroll
        for (int i = 0; i < 8; ++i) {
            reinterpret_cast<float4*>(wA)[i] = pA[i];
            reinterpret_cast<float4*>(wB)[i] = pB[i];
            reinterpret_cast<float4*>(wC)[i] = pC[i];
            reinterpret_cast<float4*>(wD)[i] = pD[i];
        }
        bA = bih[wv * 96 + rA];  bB = bih[wv * 96 + rB];
        bC = bhh[wv * 96 + rA];  bD = bhh[wv * 96 + rB];
        if (ln < HH) v_h = hid[(size_t)(wv * BB + b) * HH + ln];
    } else {
        const int r = ln & 31;
        const float4* p1 = reinterpret_cast<const float4*>(W1 + (size_t)r * HH);
        const float4* p2 = reinterpret_cast<const float4*>(W2 + (size_t)r * HH);
        const float4* p3 = reinterpret_cast<const float4*>(W3 + (size_t)r * HH);
        #pragma unroll
        for (int i = 0; i < 8; ++i) {
            reinterpret_cast<float4*>(wA)[i] = p1[i];
            reinterpret_cast<float4*>(wB)[i] = p2[i];
            reinterpret_cast<float4*>(wC)[i] = p3[i];
        }
        bA = b1[r];  bB = b2[r];  bC = b3[r];
    }
    __syncthreads();

    float* const out_seq = out + (size_t)b * TT * HH;
    float* const out_hf  = out + (size_t)BB * TT * HH;

    for (int tau = 0; tau < TT + 6; ++tau) {
        const int cur = tau & 1, prv = cur ^ 1;

        if (wv == 3) {
            // ---- emb chunk refill (1/64 ticks) ----
            if ((tau & (CH - 1)) == 0) {
                const int cn = (tau >> 6) + 1;
                if (cn < TT / CH) {
                    float4*       edst = reinterpret_cast<float4*>(&ebuf[cn & 1][0][0]);
                    const float4* esrc = reinterpret_cast<const float4*>(emb);
                    const int base = cn * CH;
                    #pragma unroll
                    for (int k = 0; k < 8; ++k) {
                        const int task = k * 64 + ln, row = task >> 3, q = task & 7;
                        edst[row * 8 + q] = esrc[(size_t)idxbuf[base + row] * 8 + q];
                    }
                }
            }
            // ---- stage 1: y1(tau) ----
            float y1 = 0.f, y2 = 0.f;
            if (tau < TT) {
                const float ve = ebuf[(tau >> 6) & 1][tau & (CH - 1)][ln & 31];
                float a0 = bA, a1 = 0.f;
                #pragma unroll
                for (int k = 0; k < 32; k += 2) {
                    const float e0 = rlane(ve, k), e1 = rlane(ve, k + 1);
                    a0 = fmaf(wA[k],     e0, a0);
                    a1 = fmaf(wA[k + 1], e1, a1);
                }
                y1 = fmaxf(a0 + a1, 0.f);
            }
            // ---- stage 2: y2(tau-1) ----
            if (tau >= 1 && tau - 1 < TT) {
                float a0 = bB, a1 = 0.f;
                #pragma unroll
                for (int k = 0; k < 32; k += 2) {
                    const float e0 = rlane(v_y1p, k), e1 = rlane(v_y1p, k + 1);
                    a0 = fmaf(wB[k],     e0, a0);
                    a1 = fmaf(wB[k + 1], e1, a1);
                }
                y2 = fmaxf(a0 + a1, 0.f);
            }
            // ---- stage 3: y3(tau-2) -> xstream[0] ----
            if (tau >= 2 && tau - 2 < TT) {
                float a0 = bC, a1 = 0.f;
                #pragma unroll
                for (int k = 0; k < 32; k += 2) {
                    const float e0 = rlane(v_y2p, k), e1 = rlane(v_y2p, k + 1);
                    a0 = fmaf(wC[k],     e0, a0);
                    a1 = fmaf(wC[k + 1], e1, a1);
                }
                const float y3 = fmaxf(a0 + a1, 0.f);
                if (ln < HH) xstream[0][cur][ln] = y3;
            }
            if (tau < TT)                 v_y1p = y1;
            if (tau >= 1 && tau - 1 < TT) v_y2p = y2;
        } else {
            const int t = tau - 3 - wv;
            // ---- wave 2: batched output flush (1/16 ticks) ----
            if (wv == 2) {
                const int t2 = tau - 5;
                if (t2 >= 16 && t2 <= TT && (t2 & 15) == 0) {
                    const int tc0 = t2 - 16;
                    #pragma unroll
                    for (int k = 0; k < 2; ++k) {
                        const int task = k * 64 + ln, row = task >> 3, q = task & 7;
                        const float4 v = *reinterpret_cast<const float4*>(&obuf[(tc0 + row) & 31][q * 4]);
                        *reinterpret_cast<float4*>(&out_seq[(size_t)(tc0 + row) * HH + q * 4]) = v;
                    }
                }
            }
            if (t >= 0 && t < TT) {
                const float vx = xstream[wv][prv][ln & 31];
                // gi dots (SGPR broadcast of x)
                float ia0 = bA, ia1 = 0.f, ib0 = bB, ib1 = 0.f;
                #pragma unroll
                for (int k = 0; k < 32; k += 2) {
                    const float x0 = rlane(vx, k), x1 = rlane(vx, k + 1);
                    ia0 = fmaf(wA[k],     x0, ia0);
                    ia1 = fmaf(wA[k + 1], x1, ia1);
                    ib0 = fmaf(wB[k],     x0, ib0);
                    ib1 = fmaf(wB[k + 1], x1, ib1);
                }
                // gh dots (SGPR broadcast of h)
                float ha0 = bC, ha1 = 0.f, hb0 = bD, hb1 = 0.f;
                #pragma unroll
                for (int k = 0; k < 32; k += 2) {
                    const float h0 = rlane(v_h, k), h1 = rlane(v_h, k + 1);
                    ha0 = fmaf(wC[k],     h0, ha0);
                    ha1 = fmaf(wC[k + 1], h1, ha1);
                    hb0 = fmaf(wD[k],     h0, hb0);
                    hb1 = fmaf(wD[k + 1], h1, hb1);
                }
                const float iA = ia0 + ia1;   // lane j<32: i_r[j]; lane 32+j: i_z[j]
                const float iB = ib0 + ib1;   // lane j<32: i_n[j]
                const float hA = ha0 + ha1;   // h_r / h_z
                const float hB = hb0 + hb1;   // h_n
                const float iZ = __shfl_down(iA, 32);
                const float hZ = __shfl_down(hA, 32);
                const float r  = sigm(iA + hA);
                const float z  = sigm(iZ + hZ);
                const float n  = tanh_fast(fmaf(r, hB, iB));
                const float hn = fmaf(z, v_h - n, n);   // (1-z)*n + z*h_prev
                v_h = hn;                                // lanes 0-31 meaningful
                if (ln < HH) {
                    if (wv < 2) xstream[wv + 1][cur][ln] = hn;
                    else        obuf[t & 31][ln] = hn;
                    if (t == TT - 1) out_hf[(size_t)(wv * BB + b) * HH + ln] = hn;
                }
            }
        }
        __syncthreads();
    }
}

extern "C" void kernel_launch(void* const* d_in, const int* in_sizes, int n_in,
                              void* d_out, int out_size, void* d_ws, size_t ws_size,
                              hipStream_t stream) {
    const int*   x   = (const int*)  d_in[0];
    const float* hid = (const float*)d_in[1];
    const float* emb = (const float*)d_in[2];
    const float* W1  = (const float*)d_in[3];
    const float* b1  = (const float*)d_in[4];
    const float* W2  = (const float*)d_in[5];
    const float* b2  = (const float*)d_in[6];
    const float* W3  = (const float*)d_in[7];
    const float* b3  = (const float*)d_in[8];
    const float* Wih = (const float*)d_in[9];
    const float* Whh = (const float*)d_in[10];
    const float* bih = (const float*)d_in[11];
    const float* bhh = (const float*)d_in[12];

    rnn_fused<<<dim3(BB), dim3(NT), 0, stream>>>(
        x, hid, emb, W1, b1, W2, b2, W3, b3, Wih, Whh, bih, bhh, (float*)d_out);
}